// Round 1
// baseline (310.556 us; speedup 1.0000x reference)
//
#include <hip/hip_runtime.h>

// Problem constants
// B=2, S=2048, D=1024, H=16, HD=64, M = B*S = 4096

typedef __bf16 bf16;
typedef bf16  bf16x8 __attribute__((ext_vector_type(8)));
typedef bf16  bf16x4 __attribute__((ext_vector_type(4)));
typedef float f32x4  __attribute__((ext_vector_type(4)));

typedef const __attribute__((address_space(1))) void* gptr_t;
typedef __attribute__((address_space(3))) void*       sptr_t;

__device__ __forceinline__ void gload_lds16(const void* g, void* l) {
  __builtin_amdgcn_global_load_lds((gptr_t)g, (sptr_t)l, 16, 0, 0);
}

// ---------------------------------------------------------------- fp32 -> bf16
__global__ __launch_bounds__(256) void f2bf_kernel(const float* __restrict__ in,
                                                   bf16* __restrict__ out, int n4) {
  int i = blockIdx.x * 256 + threadIdx.x;
  if (i < n4) {
    const float4 v = reinterpret_cast<const float4*>(in)[i];
    bf16x4 o;
    o[0] = (bf16)v.x; o[1] = (bf16)v.y; o[2] = (bf16)v.z; o[3] = (bf16)v.w;
    reinterpret_cast<bf16x4*>(out)[i] = o;
  }
}

// ---------------------------------------------------------------- RoPE tables
__global__ __launch_bounds__(256) void rope_tab_kernel(float* __restrict__ ctab,
                                                       float* __restrict__ stab) {
  int idx = blockIdx.x * 256 + threadIdx.x;
  if (idx >= 2048 * 32) return;
  int s = idx >> 5, p = idx & 31;
  double theta = exp2(-(double)p * (13.287712379549449 / 32.0)); // 10000^(-p/32)
  double ang = (double)s * theta;
  ctab[idx] = (float)cos(ang);
  stab[idx] = (float)sin(ang);
}

// ---------------------------------------------------------------- QKV GEMM
// C[m][n] = sum_k x[m][k] * W[n][k] + bias[n]; epilogue: RoPE (z<2), Q scale.
// m97 structure: 128x128 tile, BK=32, 4 waves, global_load_lds width 16.
__global__ __launch_bounds__(256) void qkv_gemm_kernel(
    const bf16* __restrict__ xb, const bf16* __restrict__ wqb,
    const bf16* __restrict__ wkb, const bf16* __restrict__ wvb,
    const float* __restrict__ bq, const float* __restrict__ bk2,
    const float* __restrict__ bv, const float* __restrict__ ctab,
    const float* __restrict__ stab, bf16* __restrict__ qb,
    bf16* __restrict__ kb, bf16* __restrict__ vb) {
  const int z = blockIdx.z;
  const bf16* W = (z == 0) ? wqb : (z == 1) ? wkb : wvb;
  const float* bias = (z == 0) ? bq : (z == 1) ? bk2 : bv;
  bf16* dst = (z == 0) ? qb : (z == 1) ? kb : vb;

  __shared__ bf16 As[128 * 32];
  __shared__ bf16 Bs[128 * 32];

  const int tid = threadIdx.x;
  const int wid = tid >> 6;
  const int l = tid & 63;
  const int lg = l >> 4, lc = l & 15;
  const int wr = wid >> 1, wc = wid & 1;
  const int m0 = blockIdx.x * 128, n0 = blockIdx.y * 128;

  f32x4 acc[4][4] = {};

  const int arow = tid >> 2;          // 0..63
  const int acol = (tid & 3) * 8;     // 0,8,16,24
  const bf16* asrc = xb + (size_t)(m0 + arow) * 1024 + acol;
  const bf16* bsrc = W + (size_t)(n0 + arow) * 1024 + acol;
  char* alds = (char*)As + wid * 1024;
  char* blds = (char*)Bs + wid * 1024;

  for (int k0 = 0; k0 < 1024; k0 += 32) {
    gload_lds16(asrc + k0, alds);
    gload_lds16(asrc + 64 * 1024 + k0, alds + 4096);
    gload_lds16(bsrc + k0, blds);
    gload_lds16(bsrc + 64 * 1024 + k0, blds + 4096);
    __syncthreads();
    bf16x8 af[4], bfr[4];
#pragma unroll
    for (int i = 0; i < 4; ++i)
      af[i] = *reinterpret_cast<const bf16x8*>(
          (const char*)As + ((wr * 64 + i * 16 + lc) * 64 + lg * 16));
#pragma unroll
    for (int j = 0; j < 4; ++j)
      bfr[j] = *reinterpret_cast<const bf16x8*>(
          (const char*)Bs + ((wc * 64 + j * 16 + lc) * 64 + lg * 16));
#pragma unroll
    for (int i = 0; i < 4; ++i)
#pragma unroll
      for (int j = 0; j < 4; ++j)
        acc[i][j] = __builtin_amdgcn_mfma_f32_16x16x32_bf16(af[i], bfr[j],
                                                            acc[i][j], 0, 0, 0);
    __syncthreads();
  }

  // Epilogue: bias, RoPE for Q/K, scale Q by 0.125*log2(e), write bf16.
#pragma unroll
  for (int i = 0; i < 4; ++i)
#pragma unroll
    for (int j = 0; j < 4; ++j) {
      const int nb = n0 + wc * 64 + j * 16 + lc;
      const float bval = bias[nb];
#pragma unroll
      for (int r = 0; r < 4; ++r) {
        const int m = m0 + wr * 64 + i * 16 + lg * 4 + r;
        const float val = acc[i][j][r] + bval;
        if (z == 2) {
          dst[(size_t)m * 1024 + nb] = (bf16)val;
        } else {
          const int s = m & 2047;
          const int pi = (nb & 63) >> 1;
          const float c = ctab[s * 32 + pi];
          const float sn = stab[s * 32 + pi];
          const float part = __shfl_xor(val, 1, 64);
          // even lane: xr*c - xi*s ; odd lane: xr*s + xi*c  (xr=even elem)
          float res = (nb & 1) ? fmaf(part, sn, val * c)
                               : fmaf(-part, sn, val * c);
          if (z == 0) res *= 0.18033688011112042f;  // (1/8) * log2(e)
          dst[(size_t)m * 1024 + nb] = (bf16)res;
        }
      }
    }
}

// ---------------------------------------------------------------- V transpose
// vb [4096][1024] -> vt [bh=32][hd=64][s=2048]
__global__ __launch_bounds__(256) void vtrans_kernel(const bf16* __restrict__ vb,
                                                     bf16* __restrict__ vt) {
  __shared__ bf16 tile[64][65];
  const int bh = blockIdx.y, b = bh >> 4, h = bh & 15;
  const int s0 = blockIdx.x * 64;
  const int t = threadIdx.x;
#pragma unroll
  for (int idx = t; idx < 4096; idx += 256) {
    int r = idx >> 6, c = idx & 63;
    tile[r][c] = vb[(size_t)(b * 2048 + s0 + r) * 1024 + h * 64 + c];
  }
  __syncthreads();
#pragma unroll
  for (int idx = t; idx < 4096; idx += 256) {
    int d = idx >> 6, r = idx & 63;
    vt[(size_t)(bh * 64 + d) * 2048 + s0 + r] = tile[r][d];
  }
}

// ---------------------------------------------------------------- Attention
// Flash-style, per block: 128 Q rows of one (b,h); 4 waves x 32 rows each.
// KTILE=64. Scores already scaled by 0.125*log2e (folded into Q) -> exp2 domain.
__global__ __launch_bounds__(256) void attn_kernel(const bf16* __restrict__ qb,
                                                   const bf16* __restrict__ kb,
                                                   const bf16* __restrict__ vt,
                                                   float* __restrict__ out) {
  const int tid = threadIdx.x;
  const int wid = tid >> 6;
  const int l = tid & 63;
  const int lg = l >> 4, lc = l & 15;
  const int q0 = blockIdx.x * 128;
  const int bh = blockIdx.y;
  const int b = bh >> 4, h = bh & 15;

  __shared__ bf16 plds[4 * 32 * 64];  // per-wave 32x64 P tile, XOR-swizzled
  char* pl = (char*)plds + wid * 4096;

  const bf16* Q = qb + (size_t)(b * 2048 + q0 + wid * 32) * 1024 + h * 64;
  const bf16* K = kb + (size_t)(b * 2048) * 1024 + h * 64;
  const bf16* V = vt + (size_t)(bh * 64) * 2048;

  bf16x8 qf[2][2];
#pragma unroll
  for (int i = 0; i < 2; ++i)
#pragma unroll
    for (int kk = 0; kk < 2; ++kk)
      qf[i][kk] = *reinterpret_cast<const bf16x8*>(
          Q + (size_t)(i * 16 + lc) * 1024 + kk * 32 + lg * 8);

  f32x4 o[2][4] = {};
  float mrun[2][4], lrun[2][4];
#pragma unroll
  for (int i = 0; i < 2; ++i)
#pragma unroll
    for (int r = 0; r < 4; ++r) { mrun[i][r] = -1e30f; lrun[i][r] = 0.f; }

  for (int kt = 0; kt < 32; ++kt) {
    f32x4 sacc[2][4] = {};
#pragma unroll
    for (int kk = 0; kk < 2; ++kk) {
#pragma unroll
      for (int j = 0; j < 4; ++j) {
        bf16x8 kf = *reinterpret_cast<const bf16x8*>(
            K + (size_t)(kt * 64 + j * 16 + lc) * 1024 + kk * 32 + lg * 8);
#pragma unroll
        for (int i = 0; i < 2; ++i)
          sacc[i][j] = __builtin_amdgcn_mfma_f32_16x16x32_bf16(qf[i][kk], kf,
                                                               sacc[i][j], 0, 0, 0);
      }
    }
    // Online softmax (exp2 domain); row stats across 16-lane groups.
#pragma unroll
    for (int i = 0; i < 2; ++i)
#pragma unroll
      for (int r = 0; r < 4; ++r) {
        float tm = fmaxf(fmaxf(sacc[i][0][r], sacc[i][1][r]),
                         fmaxf(sacc[i][2][r], sacc[i][3][r]));
#pragma unroll
        for (int d = 1; d < 16; d <<= 1) tm = fmaxf(tm, __shfl_xor(tm, d, 64));
        const float mn = fmaxf(mrun[i][r], tm);
        const float corr = exp2f(mrun[i][r] - mn);
        mrun[i][r] = mn;
        float ts = 0.f;
#pragma unroll
        for (int j = 0; j < 4; ++j) {
          const float p = exp2f(sacc[i][j][r] - mn);
          sacc[i][j][r] = p;
          ts += p;
        }
#pragma unroll
        for (int d = 1; d < 16; d <<= 1) ts += __shfl_xor(ts, d, 64);
        lrun[i][r] = lrun[i][r] * corr + ts;
#pragma unroll
        for (int jd = 0; jd < 4; ++jd) o[i][jd][r] *= corr;
      }
    // P -> LDS (bf16), XOR swizzle to kill the 128B-stride bank conflict.
#pragma unroll
    for (int i = 0; i < 2; ++i)
#pragma unroll
      for (int j = 0; j < 4; ++j)
#pragma unroll
        for (int r = 0; r < 4; ++r) {
          const int row = i * 16 + lg * 4 + r;
          const int cb = (j * 16 + lc) * 2;
          *reinterpret_cast<bf16*>(pl + row * 128 + (cb ^ ((row & 7) << 4))) =
              (bf16)sacc[i][j][r];
        }
    __syncthreads();
    // PV: A = P (from LDS), B = V^T rows (direct 16B global loads).
#pragma unroll
    for (int kk = 0; kk < 2; ++kk) {
      bf16x8 pa[2];
#pragma unroll
      for (int i = 0; i < 2; ++i)
        pa[i] = *reinterpret_cast<const bf16x8*>(
            pl + (i * 16 + lc) * 128 + ((kk * 64 + lg * 16) ^ ((lc & 7) << 4)));
#pragma unroll
      for (int jd = 0; jd < 4; ++jd) {
        bf16x8 vf = *reinterpret_cast<const bf16x8*>(
            V + (size_t)(jd * 16 + lc) * 2048 + kt * 64 + kk * 32 + lg * 8);
#pragma unroll
        for (int i = 0; i < 2; ++i)
          o[i][jd] = __builtin_amdgcn_mfma_f32_16x16x32_bf16(pa[i], vf,
                                                             o[i][jd], 0, 0, 0);
      }
    }
  }

  const size_t orow0 = (size_t)(b * 2048 + q0 + wid * 32);
#pragma unroll
  for (int i = 0; i < 2; ++i)
#pragma unroll
    for (int r = 0; r < 4; ++r) {
      const float inv = 1.f / lrun[i][r];
#pragma unroll
      for (int jd = 0; jd < 4; ++jd)
        out[(orow0 + i * 16 + lg * 4 + r) * 1024 + h * 64 + jd * 16 + lc] =
            o[i][jd][r] * inv;
    }
}

// ---------------------------------------------------------------- launch
extern "C" void kernel_launch(void* const* d_in, const int* in_sizes, int n_in,
                              void* d_out, int out_size, void* d_ws, size_t ws_size,
                              hipStream_t stream) {
  const float* x  = (const float*)d_in[0];
  const float* wq = (const float*)d_in[1];
  const float* bq = (const float*)d_in[2];
  const float* wk = (const float*)d_in[3];
  const float* bk = (const float*)d_in[4];
  const float* wv = (const float*)d_in[5];
  const float* bv = (const float*)d_in[6];
  float* out = (float*)d_out;

  char* ws = (char*)d_ws;
  bf16* xb  = (bf16*)(ws);                    // 8,388,608 B
  bf16* wqb = (bf16*)(ws + 8388608);          // 2,097,152
  bf16* wkb = (bf16*)(ws + 10485760);         // 2,097,152
  bf16* wvb = (bf16*)(ws + 12582912);         // 2,097,152
  bf16* qb  = (bf16*)(ws + 14680064);         // 8,388,608
  bf16* kb  = (bf16*)(ws + 23068672);         // 8,388,608
  bf16* vb  = (bf16*)(ws + 31457280);         // 8,388,608
  bf16* vt  = (bf16*)(ws + 39845888);         // 8,388,608
  float* ctab = (float*)(ws + 48234496);      // 262,144
  float* stab = (float*)(ws + 48496640);      // 262,144

  f2bf_kernel<<<4096, 256, 0, stream>>>(x, xb, 1048576);
  f2bf_kernel<<<1024, 256, 0, stream>>>(wq, wqb, 262144);
  f2bf_kernel<<<1024, 256, 0, stream>>>(wk, wkb, 262144);
  f2bf_kernel<<<1024, 256, 0, stream>>>(wv, wvb, 262144);
  rope_tab_kernel<<<256, 256, 0, stream>>>(ctab, stab);

  qkv_gemm_kernel<<<dim3(32, 8, 3), 256, 0, stream>>>(
      xb, wqb, wkb, wvb, bq, bk, bv, ctab, stab, qb, kb, vb);

  vtrans_kernel<<<dim3(32, 32), 256, 0, stream>>>(vb, vt);

  attn_kernel<<<dim3(16, 32), 256, 0, stream>>>(qb, kb, vt, out);
}

// Round 2
// 258.937 us; speedup vs baseline: 1.1993x; 1.1993x over previous
//
#include <hip/hip_runtime.h>

// Problem constants: B=2, S=2048, D=1024, H=16, HD=64, M = B*S = 4096

typedef __bf16 bf16;
typedef bf16  bf16x8 __attribute__((ext_vector_type(8)));
typedef bf16  bf16x4 __attribute__((ext_vector_type(4)));
typedef float f32x4  __attribute__((ext_vector_type(4)));
typedef float f32x16 __attribute__((ext_vector_type(16)));

typedef const __attribute__((address_space(1))) void* gptr_t;
typedef __attribute__((address_space(3))) void*       sptr_t;

__device__ __forceinline__ void gload_lds16(const void* g, void* l) {
  __builtin_amdgcn_global_load_lds((gptr_t)g, (sptr_t)l, 16, 0, 0);
}

// ---------------------------------------------------------------- fp32 -> bf16
__global__ __launch_bounds__(256) void f2bf_kernel(const float* __restrict__ in,
                                                   bf16* __restrict__ out, int n4) {
  int i = blockIdx.x * 256 + threadIdx.x;
  if (i < n4) {
    const float4 v = reinterpret_cast<const float4*>(in)[i];
    bf16x4 o;
    o[0] = (bf16)v.x; o[1] = (bf16)v.y; o[2] = (bf16)v.z; o[3] = (bf16)v.w;
    reinterpret_cast<bf16x4*>(out)[i] = o;
  }
}

// ---------------------------------------------------------------- RoPE tables
__global__ __launch_bounds__(256) void rope_tab_kernel(float* __restrict__ ctab,
                                                       float* __restrict__ stab) {
  int idx = blockIdx.x * 256 + threadIdx.x;
  if (idx >= 2048 * 32) return;
  int s = idx >> 5, p = idx & 31;
  double theta = exp2(-(double)p * (13.287712379549449 / 32.0)); // 10000^(-p/32)
  double ang = (double)s * theta;
  ctab[idx] = (float)cos(ang);
  stab[idx] = (float)sin(ang);
}

// ---------------------------------------------------------------- QKV GEMM
// C[m][n] = sum_k x[m][k] * W[n][k] + bias[n]; epilogue: RoPE (z<2), Q scale.
__global__ __launch_bounds__(256) void qkv_gemm_kernel(
    const bf16* __restrict__ xb, const bf16* __restrict__ wqb,
    const bf16* __restrict__ wkb, const bf16* __restrict__ wvb,
    const float* __restrict__ bq, const float* __restrict__ bk2,
    const float* __restrict__ bv, const float* __restrict__ ctab,
    const float* __restrict__ stab, bf16* __restrict__ qb,
    bf16* __restrict__ kb, bf16* __restrict__ vb) {
  const int z = blockIdx.z;
  const bf16* W = (z == 0) ? wqb : (z == 1) ? wkb : wvb;
  const float* bias = (z == 0) ? bq : (z == 1) ? bk2 : bv;
  bf16* dst = (z == 0) ? qb : (z == 1) ? kb : vb;

  __shared__ bf16 As[128 * 32];
  __shared__ bf16 Bs[128 * 32];

  const int tid = threadIdx.x;
  const int wid = tid >> 6;
  const int l = tid & 63;
  const int lg = l >> 4, lc = l & 15;
  const int wr = wid >> 1, wc = wid & 1;
  const int m0 = blockIdx.x * 128, n0 = blockIdx.y * 128;

  f32x4 acc[4][4] = {};

  const int arow = tid >> 2;          // 0..63
  const int acol = (tid & 3) * 8;     // 0,8,16,24
  const bf16* asrc = xb + (size_t)(m0 + arow) * 1024 + acol;
  const bf16* bsrc = W + (size_t)(n0 + arow) * 1024 + acol;
  char* alds = (char*)As + wid * 1024;
  char* blds = (char*)Bs + wid * 1024;

  for (int k0 = 0; k0 < 1024; k0 += 32) {
    gload_lds16(asrc + k0, alds);
    gload_lds16(asrc + 64 * 1024 + k0, alds + 4096);
    gload_lds16(bsrc + k0, blds);
    gload_lds16(bsrc + 64 * 1024 + k0, blds + 4096);
    __syncthreads();
    bf16x8 af[4], bfr[4];
#pragma unroll
    for (int i = 0; i < 4; ++i)
      af[i] = *reinterpret_cast<const bf16x8*>(
          (const char*)As + ((wr * 64 + i * 16 + lc) * 64 + lg * 16));
#pragma unroll
    for (int j = 0; j < 4; ++j)
      bfr[j] = *reinterpret_cast<const bf16x8*>(
          (const char*)Bs + ((wc * 64 + j * 16 + lc) * 64 + lg * 16));
#pragma unroll
    for (int i = 0; i < 4; ++i)
#pragma unroll
      for (int j = 0; j < 4; ++j)
        acc[i][j] = __builtin_amdgcn_mfma_f32_16x16x32_bf16(af[i], bfr[j],
                                                            acc[i][j], 0, 0, 0);
    __syncthreads();
  }

#pragma unroll
  for (int i = 0; i < 4; ++i)
#pragma unroll
    for (int j = 0; j < 4; ++j) {
      const int nb = n0 + wc * 64 + j * 16 + lc;
      const float bval = bias[nb];
#pragma unroll
      for (int r = 0; r < 4; ++r) {
        const int m = m0 + wr * 64 + i * 16 + lg * 4 + r;
        const float val = acc[i][j][r] + bval;
        if (z == 2) {
          dst[(size_t)m * 1024 + nb] = (bf16)val;
        } else {
          const int s = m & 2047;
          const int pi = (nb & 63) >> 1;
          const float c = ctab[s * 32 + pi];
          const float sn = stab[s * 32 + pi];
          const float part = __shfl_xor(val, 1, 64);
          float res = (nb & 1) ? fmaf(part, sn, val * c)
                               : fmaf(-part, sn, val * c);
          if (z == 0) res *= 0.18033688011112042f;  // (1/8) * log2(e)
          dst[(size_t)m * 1024 + nb] = (bf16)res;
        }
      }
    }
}

// ---------------------------------------------------------------- V transpose
// vb [4096][1024] -> vt [bh=32][hd=64][s=2048]
__global__ __launch_bounds__(256) void vtrans_kernel(const bf16* __restrict__ vb,
                                                     bf16* __restrict__ vt) {
  __shared__ bf16 tile[64][65];
  const int bh = blockIdx.y, b = bh >> 4, h = bh & 15;
  const int s0 = blockIdx.x * 64;
  const int t = threadIdx.x;
#pragma unroll
  for (int idx = t; idx < 4096; idx += 256) {
    int r = idx >> 6, c = idx & 63;
    tile[r][c] = vb[(size_t)(b * 2048 + s0 + r) * 1024 + h * 64 + c];
  }
  __syncthreads();
#pragma unroll
  for (int idx = t; idx < 4096; idx += 256) {
    int d = idx >> 6, r = idx & 63;
    vt[(size_t)(bh * 64 + d) * 2048 + s0 + r] = tile[r][d];
  }
}

// ---------------------------------------------------------------- pack helpers
__device__ __forceinline__ unsigned pkbf(float a, float b) {
  union { bf16 h[2]; unsigned u; } t;
  t.h[0] = (bf16)a; t.h[1] = (bf16)b;
  return t.u;
}

// ---------------------------------------------------------------- Attention v2
// Swapped QK^T (S^T = K.Q^T) via 32x32x16 MFMA; fully in-register online
// softmax (exp2 domain, scale folded into Q); lane-exchange to PV B-operand;
// no LDS, no barriers in the k-loop. 1 wave = 32 q rows; 4 waves/block.
__global__ __launch_bounds__(256) void attn_kernel(const bf16* __restrict__ qb,
                                                   const bf16* __restrict__ kb,
                                                   const bf16* __restrict__ vt,
                                                   float* __restrict__ out) {
  const int tid = threadIdx.x;
  const int wid = tid >> 6;
  const int l = tid & 63;
  const int lc = l & 31;      // q index within tile (MFMA C col)
  const int hi = l >> 5;      // half-wave
  const int bh = blockIdx.y;
  const int b = bh >> 4, h = bh & 15;
  const int q0 = blockIdx.x * 128 + wid * 32;

  const bf16* Q = qb + (size_t)(b * 2048 + q0) * 1024 + h * 64;
  const bf16* K = kb + (size_t)(b * 2048) * 1024 + h * 64;
  const bf16* V = vt + (size_t)bh * 64 * 2048;

  // Q fragment (B-operand of QK^T): qf[md][t] = Q[q0+lc][md*16 + hi*8 + t]
  bf16x8 qf[4];
#pragma unroll
  for (int md = 0; md < 4; ++md)
    qf[md] = *reinterpret_cast<const bf16x8*>(Q + (size_t)lc * 1024 + md * 16 + hi * 8);

  f32x16 o0 = {};  // O^T rows d = 0..31  (d = (r&3)+8*(r>>2)+4*hi)
  f32x16 o1 = {};  // O^T rows d = 32..63
  float mrun = -1e30f, lrun = 0.f;
  const int sb = (hi ^ 1) * 2;  // exchange pre-select base

  for (int kt = 0; kt < 64; ++kt) {
    // ---- S^T tile [32 k][32 q]: A = K rows, B = Q
    const bf16* Krow = K + (size_t)(kt * 32 + lc) * 1024 + hi * 8;
    f32x16 s = {};
#pragma unroll
    for (int md = 0; md < 4; ++md) {
      bf16x8 kf = *reinterpret_cast<const bf16x8*>(Krow + md * 16);
      s = __builtin_amdgcn_mfma_f32_32x32x16_bf16(kf, qf[md], s, 0, 0, 0);
    }
    // lane holds S^T[k_local=(r&3)+8*(r>>2)+4*hi][q=lc], one q per lane.

    // ---- online softmax, in-register (exp2 domain)
    float tm = s[0];
#pragma unroll
    for (int r = 1; r < 16; ++r) tm = fmaxf(tm, s[r]);
    tm = fmaxf(tm, __shfl_xor(tm, 32, 64));
    if (!__all(tm <= mrun + 8.0f)) {   // T13 defer-max
      const float mn = fmaxf(mrun, tm);
      const float corr = exp2f(mrun - mn);
      mrun = mn;
      lrun *= corr;
#pragma unroll
      for (int r = 0; r < 16; ++r) { o0[r] *= corr; o1[r] *= corr; }
    }
    float ts = 0.f;
#pragma unroll
    for (int r = 0; r < 16; ++r) {
      s[r] = exp2f(s[r] - mrun);
      ts += s[r];
    }
    ts += __shfl_xor(ts, 32, 64);
    lrun += ts;

    // ---- pack P^T to bf16 pairs: pk[w] holds k_local {kb, kb+1},
    //      kb = (w&1)*2 + 8*(w>>1) + 4*hi
    unsigned pw[8];
#pragma unroll
    for (int w = 0; w < 8; ++w) pw[w] = pkbf(s[2 * w], s[2 * w + 1]);

    // ---- exchange halves: rx[v] = partner's pk[w_list(hi)[v]]
    unsigned rx0 = __shfl_xor(pw[sb + 0], 32, 64);
    unsigned rx1 = __shfl_xor(pw[sb + 1], 32, 64);
    unsigned rx2 = __shfl_xor(pw[4 + sb + 0], 32, 64);
    unsigned rx3 = __shfl_xor(pw[4 + sb + 1], 32, 64);

    // ---- assemble PV B-fragments (P^T[k16][q]) for s16 = 0,1
    union { unsigned u[4]; bf16x8 v; } bf0, bf1;
    if (hi == 0) {
      bf0.u[0] = pw[0]; bf0.u[1] = pw[1]; bf0.u[2] = rx0; bf0.u[3] = rx1;
      bf1.u[0] = pw[4]; bf1.u[1] = pw[5]; bf1.u[2] = rx2; bf1.u[3] = rx3;
    } else {
      bf0.u[0] = rx0; bf0.u[1] = rx1; bf0.u[2] = pw[2]; bf0.u[3] = pw[3];
      bf1.u[0] = rx2; bf1.u[1] = rx3; bf1.u[2] = pw[6]; bf1.u[3] = pw[7];
    }

    // ---- PV: A = V^T rows (d), k = 16 per MFMA
    const bf16* Vb = V + (size_t)lc * 2048 + kt * 32 + hi * 8;
    bf16x8 vf00 = *reinterpret_cast<const bf16x8*>(Vb);
    bf16x8 vf01 = *reinterpret_cast<const bf16x8*>(Vb + 16);
    bf16x8 vf10 = *reinterpret_cast<const bf16x8*>(Vb + 32 * 2048);
    bf16x8 vf11 = *reinterpret_cast<const bf16x8*>(Vb + 32 * 2048 + 16);
    o0 = __builtin_amdgcn_mfma_f32_32x32x16_bf16(vf00, bf0.v, o0, 0, 0, 0);
    o0 = __builtin_amdgcn_mfma_f32_32x32x16_bf16(vf01, bf1.v, o0, 0, 0, 0);
    o1 = __builtin_amdgcn_mfma_f32_32x32x16_bf16(vf10, bf0.v, o1, 0, 0, 0);
    o1 = __builtin_amdgcn_mfma_f32_32x32x16_bf16(vf11, bf1.v, o1, 0, 0, 0);
  }

  // ---- epilogue: out[b][q][h*64+d] = O^T[d][q] / lrun, f32x4 stores
  const float inv = 1.f / lrun;
  float* orow = out + (size_t)(b * 2048 + q0 + lc) * 1024 + h * 64;
#pragma unroll
  for (int g = 0; g < 4; ++g) {
    f32x4 v0, v1;
#pragma unroll
    for (int e = 0; e < 4; ++e) { v0[e] = o0[g * 4 + e] * inv; v1[e] = o1[g * 4 + e] * inv; }
    *reinterpret_cast<f32x4*>(orow + g * 8 + 4 * hi) = v0;
    *reinterpret_cast<f32x4*>(orow + 32 + g * 8 + 4 * hi) = v1;
  }
}

// ---------------------------------------------------------------- launch
extern "C" void kernel_launch(void* const* d_in, const int* in_sizes, int n_in,
                              void* d_out, int out_size, void* d_ws, size_t ws_size,
                              hipStream_t stream) {
  const float* x  = (const float*)d_in[0];
  const float* wq = (const float*)d_in[1];
  const float* bq = (const float*)d_in[2];
  const float* wk = (const float*)d_in[3];
  const float* bk = (const float*)d_in[4];
  const float* wv = (const float*)d_in[5];
  const float* bv = (const float*)d_in[6];
  float* out = (float*)d_out;

  char* ws = (char*)d_ws;
  bf16* xb  = (bf16*)(ws);                    // 8,388,608 B
  bf16* wqb = (bf16*)(ws + 8388608);          // 2,097,152
  bf16* wkb = (bf16*)(ws + 10485760);         // 2,097,152
  bf16* wvb = (bf16*)(ws + 12582912);         // 2,097,152
  bf16* qb  = (bf16*)(ws + 14680064);         // 8,388,608
  bf16* kb  = (bf16*)(ws + 23068672);         // 8,388,608
  bf16* vb  = (bf16*)(ws + 31457280);         // 8,388,608
  bf16* vt  = (bf16*)(ws + 39845888);         // 8,388,608
  float* ctab = (float*)(ws + 48234496);      // 262,144
  float* stab = (float*)(ws + 48496640);      // 262,144

  f2bf_kernel<<<4096, 256, 0, stream>>>(x, xb, 1048576);
  f2bf_kernel<<<1024, 256, 0, stream>>>(wq, wqb, 262144);
  f2bf_kernel<<<1024, 256, 0, stream>>>(wk, wkb, 262144);
  f2bf_kernel<<<1024, 256, 0, stream>>>(wv, wvb, 262144);
  rope_tab_kernel<<<256, 256, 0, stream>>>(ctab, stab);

  qkv_gemm_kernel<<<dim3(32, 8, 3), 256, 0, stream>>>(
      xb, wqb, wkb, wvb, bq, bk, bv, ctab, stab, qb, kb, vb);

  vtrans_kernel<<<dim3(32, 32), 256, 0, stream>>>(vb, vt);

  attn_kernel<<<dim3(16, 32), 256, 0, stream>>>(qb, kb, vt, out);
}

// Round 3
// 257.050 us; speedup vs baseline: 1.2082x; 1.0073x over previous
//
#include <hip/hip_runtime.h>

// Problem constants: B=2, S=2048, D=1024, H=16, HD=64, M = B*S = 4096

typedef __bf16 bf16;
typedef bf16  bf16x8 __attribute__((ext_vector_type(8)));
typedef bf16  bf16x4 __attribute__((ext_vector_type(4)));
typedef float f32x4  __attribute__((ext_vector_type(4)));
typedef float f32x16 __attribute__((ext_vector_type(16)));

typedef const __attribute__((address_space(1))) void* gptr_t;
typedef __attribute__((address_space(3))) void*       sptr_t;

__device__ __forceinline__ void gload_lds16(const void* g, void* l) {
  __builtin_amdgcn_global_load_lds((gptr_t)g, (sptr_t)l, 16, 0, 0);
}

// ------------------------------------------------- fused prep: f2bf x4 + rope
__global__ __launch_bounds__(256) void prep_kernel(
    const float* __restrict__ x, const float* __restrict__ wq,
    const float* __restrict__ wk, const float* __restrict__ wv,
    bf16* __restrict__ xb, bf16* __restrict__ wqb, bf16* __restrict__ wkb,
    bf16* __restrict__ wvb, float* __restrict__ ctab, float* __restrict__ stab) {
  int g = blockIdx.x * 256 + threadIdx.x;
  const float* src;
  bf16* dst;
  int i;
  if (g < 1048576) { src = x; dst = xb; i = g; }
  else if (g < 1310720) { src = wq; dst = wqb; i = g - 1048576; }
  else if (g < 1572864) { src = wk; dst = wkb; i = g - 1310720; }
  else if (g < 1835008) { src = wv; dst = wvb; i = g - 1572864; }
  else {
    int idx = g - 1835008;
    if (idx < 65536) {
      int s = idx >> 5, p = idx & 31;
      double theta = exp2(-(double)p * (13.287712379549449 / 32.0));
      double ang = (double)s * theta;
      ctab[idx] = (float)cos(ang);
      stab[idx] = (float)sin(ang);
    }
    return;
  }
  const float4 v = reinterpret_cast<const float4*>(src)[i];
  bf16x4 o;
  o[0] = (bf16)v.x; o[1] = (bf16)v.y; o[2] = (bf16)v.z; o[3] = (bf16)v.w;
  reinterpret_cast<bf16x4*>(dst)[i] = o;
}

// ---------------------------------------------------------------- QKV GEMM
// C[m][n] = sum_k x[m][k] * W[n][k] + bias[n]; epilogue: RoPE (z<2), Q scale.
__global__ __launch_bounds__(256) void qkv_gemm_kernel(
    const bf16* __restrict__ xb, const bf16* __restrict__ wqb,
    const bf16* __restrict__ wkb, const bf16* __restrict__ wvb,
    const float* __restrict__ bq, const float* __restrict__ bk2,
    const float* __restrict__ bv, const float* __restrict__ ctab,
    const float* __restrict__ stab, bf16* __restrict__ qb,
    bf16* __restrict__ kb, bf16* __restrict__ vb) {
  const int z = blockIdx.z;
  const bf16* W = (z == 0) ? wqb : (z == 1) ? wkb : wvb;
  const float* bias = (z == 0) ? bq : (z == 1) ? bk2 : bv;
  bf16* dst = (z == 0) ? qb : (z == 1) ? kb : vb;

  __shared__ bf16 As[128 * 32];
  __shared__ bf16 Bs[128 * 32];

  const int tid = threadIdx.x;
  const int wid = tid >> 6;
  const int l = tid & 63;
  const int lg = l >> 4, lc = l & 15;
  const int wr = wid >> 1, wc = wid & 1;
  const int m0 = blockIdx.x * 128, n0 = blockIdx.y * 128;

  f32x4 acc[4][4] = {};

  const int arow = tid >> 2;          // 0..63
  const int acol = (tid & 3) * 8;     // 0,8,16,24
  const bf16* asrc = xb + (size_t)(m0 + arow) * 1024 + acol;
  const bf16* bsrc = W + (size_t)(n0 + arow) * 1024 + acol;
  char* alds = (char*)As + wid * 1024;
  char* blds = (char*)Bs + wid * 1024;

  for (int k0 = 0; k0 < 1024; k0 += 32) {
    gload_lds16(asrc + k0, alds);
    gload_lds16(asrc + 64 * 1024 + k0, alds + 4096);
    gload_lds16(bsrc + k0, blds);
    gload_lds16(bsrc + 64 * 1024 + k0, blds + 4096);
    __syncthreads();
    bf16x8 af[4], bfr[4];
#pragma unroll
    for (int i = 0; i < 4; ++i)
      af[i] = *reinterpret_cast<const bf16x8*>(
          (const char*)As + ((wr * 64 + i * 16 + lc) * 64 + lg * 16));
#pragma unroll
    for (int j = 0; j < 4; ++j)
      bfr[j] = *reinterpret_cast<const bf16x8*>(
          (const char*)Bs + ((wc * 64 + j * 16 + lc) * 64 + lg * 16));
#pragma unroll
    for (int i = 0; i < 4; ++i)
#pragma unroll
      for (int j = 0; j < 4; ++j)
        acc[i][j] = __builtin_amdgcn_mfma_f32_16x16x32_bf16(af[i], bfr[j],
                                                            acc[i][j], 0, 0, 0);
    __syncthreads();
  }

#pragma unroll
  for (int i = 0; i < 4; ++i)
#pragma unroll
    for (int j = 0; j < 4; ++j) {
      const int nb = n0 + wc * 64 + j * 16 + lc;
      const float bval = bias[nb];
#pragma unroll
      for (int r = 0; r < 4; ++r) {
        const int m = m0 + wr * 64 + i * 16 + lg * 4 + r;
        const float val = acc[i][j][r] + bval;
        if (z == 2) {
          dst[(size_t)m * 1024 + nb] = (bf16)val;
        } else {
          const int s = m & 2047;
          const int pi = (nb & 63) >> 1;
          const float c = ctab[s * 32 + pi];
          const float sn = stab[s * 32 + pi];
          const float part = __shfl_xor(val, 1, 64);
          float res = (nb & 1) ? fmaf(part, sn, val * c)
                               : fmaf(-part, sn, val * c);
          if (z == 0) res *= 0.18033688011112042f;  // (1/8) * log2(e)
          dst[(size_t)m * 1024 + nb] = (bf16)res;
        }
      }
    }
}

// ---------------------------------------------------------------- V transpose
// vb [4096][1024] -> vt [bh=32][hd=64][s=2048]
__global__ __launch_bounds__(256) void vtrans_kernel(const bf16* __restrict__ vb,
                                                     bf16* __restrict__ vt) {
  __shared__ bf16 tile[64][65];
  const int bh = blockIdx.y, b = bh >> 4, h = bh & 15;
  const int s0 = blockIdx.x * 64;
  const int t = threadIdx.x;
#pragma unroll
  for (int idx = t; idx < 4096; idx += 256) {
    int r = idx >> 6, c = idx & 63;
    tile[r][c] = vb[(size_t)(b * 2048 + s0 + r) * 1024 + h * 64 + c];
  }
  __syncthreads();
#pragma unroll
  for (int idx = t; idx < 4096; idx += 256) {
    int d = idx >> 6, r = idx & 63;
    vt[(size_t)(bh * 64 + d) * 2048 + s0 + r] = tile[r][d];
  }
}

// ---------------------------------------------------------------- pack helper
__device__ __forceinline__ unsigned pkbf(float a, float b) {
  union { bf16 h[2]; unsigned u; } t;
  t.h[0] = (bf16)a; t.h[1] = (bf16)b;
  return t.u;
}

// ---------------------------------------------------------------- Attention v3
// Swapped QK^T via 32x32x16 MFMA, in-register online softmax (exp2 domain),
// zero LDS/barriers in the k-loop. 4-way KV split within block: 4 waves share
// the same 32 q rows, each sweeps 512 kv positions; pairwise LDS merge at end.
__global__ __launch_bounds__(256) void attn_kernel(const bf16* __restrict__ qb,
                                                   const bf16* __restrict__ kb,
                                                   const bf16* __restrict__ vt,
                                                   float* __restrict__ out) {
  // LDS merge buffers: 2 slots x 64 lanes x 34 floats (stride 34 -> 2-way free)
  __shared__ float clds[2][64][34];

  const int tid = threadIdx.x;
  const int wid = tid >> 6;
  const int l = tid & 63;
  const int lc = l & 31;      // q index within tile (MFMA C col)
  const int hi = l >> 5;      // half-wave
  // XCD-aware swizzle: 2048 blocks, 8 XCDs -> same-head blocks colocate per XCD
  const int bid = blockIdx.x;
  const int swz = (bid & 7) * 256 + (bid >> 3);
  const int bh = swz >> 6;          // 0..31
  const int qt = swz & 63;          // 0..63
  const int b = bh >> 4, h = bh & 15;
  const int q0 = qt * 32;

  const bf16* Q = qb + (size_t)(b * 2048 + q0) * 1024 + h * 64;
  const bf16* K = kb + (size_t)(b * 2048) * 1024 + h * 64;
  const bf16* V = vt + (size_t)bh * 64 * 2048;

  // Q fragment (B-operand of QK^T): qf[md][t] = Q[q0+lc][md*16 + hi*8 + t]
  bf16x8 qf[4];
#pragma unroll
  for (int md = 0; md < 4; ++md)
    qf[md] = *reinterpret_cast<const bf16x8*>(Q + (size_t)lc * 1024 + md * 16 + hi * 8);

  f32x16 o0 = {};  // O^T rows d = 0..31  (d = (r&3)+8*(r>>2)+4*hi)
  f32x16 o1 = {};  // O^T rows d = 32..63
  float mrun = -1e30f, lrun = 0.f;
  const int sb = (hi ^ 1) * 2;  // exchange pre-select base

  const int kt_lo = wid * 16, kt_hi = kt_lo + 16;
  for (int kt = kt_lo; kt < kt_hi; ++kt) {
    // ---- S^T tile [32 k][32 q]: A = K rows, B = Q
    const bf16* Krow = K + (size_t)(kt * 32 + lc) * 1024 + hi * 8;
    f32x16 s = {};
#pragma unroll
    for (int md = 0; md < 4; ++md) {
      bf16x8 kf = *reinterpret_cast<const bf16x8*>(Krow + md * 16);
      s = __builtin_amdgcn_mfma_f32_32x32x16_bf16(kf, qf[md], s, 0, 0, 0);
    }
    // lane holds S^T[k_local=(r&3)+8*(r>>2)+4*hi][q=lc]

    // ---- online softmax (exp2 domain)
    float tm = s[0];
#pragma unroll
    for (int r = 1; r < 16; ++r) tm = fmaxf(tm, s[r]);
    tm = fmaxf(tm, __shfl_xor(tm, 32, 64));
    if (!__all(tm <= mrun + 8.0f)) {   // T13 defer-max
      const float mn = fmaxf(mrun, tm);
      const float corr = exp2f(mrun - mn);
      mrun = mn;
      lrun *= corr;
#pragma unroll
      for (int r = 0; r < 16; ++r) { o0[r] *= corr; o1[r] *= corr; }
    }
    float ts = 0.f;
#pragma unroll
    for (int r = 0; r < 16; ++r) {
      s[r] = exp2f(s[r] - mrun);
      ts += s[r];
    }
    ts += __shfl_xor(ts, 32, 64);
    lrun += ts;

    // ---- pack P^T to bf16 pairs
    unsigned pw[8];
#pragma unroll
    for (int w = 0; w < 8; ++w) pw[w] = pkbf(s[2 * w], s[2 * w + 1]);

    unsigned rx0 = __shfl_xor(pw[sb + 0], 32, 64);
    unsigned rx1 = __shfl_xor(pw[sb + 1], 32, 64);
    unsigned rx2 = __shfl_xor(pw[4 + sb + 0], 32, 64);
    unsigned rx3 = __shfl_xor(pw[4 + sb + 1], 32, 64);

    union { unsigned u[4]; bf16x8 v; } bf0, bf1;
    if (hi == 0) {
      bf0.u[0] = pw[0]; bf0.u[1] = pw[1]; bf0.u[2] = rx0; bf0.u[3] = rx1;
      bf1.u[0] = pw[4]; bf1.u[1] = pw[5]; bf1.u[2] = rx2; bf1.u[3] = rx3;
    } else {
      bf0.u[0] = rx0; bf0.u[1] = rx1; bf0.u[2] = pw[2]; bf0.u[3] = pw[3];
      bf1.u[0] = rx2; bf1.u[1] = rx3; bf1.u[2] = pw[6]; bf1.u[3] = pw[7];
    }

    // ---- PV: A = V^T rows (d), k = 16 per MFMA
    const bf16* Vb = V + (size_t)lc * 2048 + kt * 32 + hi * 8;
    bf16x8 vf00 = *reinterpret_cast<const bf16x8*>(Vb);
    bf16x8 vf01 = *reinterpret_cast<const bf16x8*>(Vb + 16);
    bf16x8 vf10 = *reinterpret_cast<const bf16x8*>(Vb + 32 * 2048);
    bf16x8 vf11 = *reinterpret_cast<const bf16x8*>(Vb + 32 * 2048 + 16);
    o0 = __builtin_amdgcn_mfma_f32_32x32x16_bf16(vf00, bf0.v, o0, 0, 0, 0);
    o0 = __builtin_amdgcn_mfma_f32_32x32x16_bf16(vf01, bf1.v, o0, 0, 0, 0);
    o1 = __builtin_amdgcn_mfma_f32_32x32x16_bf16(vf10, bf0.v, o1, 0, 0, 0);
    o1 = __builtin_amdgcn_mfma_f32_32x32x16_bf16(vf11, bf1.v, o1, 0, 0, 0);
  }

  // ---- pairwise merge across the 4 KV-split waves (exp2 domain)
  // round 1: waves 2,3 publish; waves 0,1 merge.  round 2: wave 1 -> wave 0.
  if (wid >= 2) {
    float* dst = &clds[wid - 2][l][0];
#pragma unroll
    for (int r = 0; r < 16; ++r) { dst[r] = o0[r]; dst[16 + r] = o1[r]; }
    dst[32] = mrun; dst[33] = lrun;
  }
  __syncthreads();
  if (wid < 2) {
    const float* src = &clds[wid][l][0];
    const float mb = src[32], lb = src[33];
    const float M = fmaxf(mrun, mb);
    const float ca = exp2f(mrun - M), cb = exp2f(mb - M);
    mrun = M;
    lrun = lrun * ca + lb * cb;
#pragma unroll
    for (int r = 0; r < 16; ++r) {
      o0[r] = o0[r] * ca + src[r] * cb;
      o1[r] = o1[r] * ca + src[16 + r] * cb;
    }
  }
  __syncthreads();
  if (wid == 1) {
    float* dst = &clds[0][l][0];
#pragma unroll
    for (int r = 0; r < 16; ++r) { dst[r] = o0[r]; dst[16 + r] = o1[r]; }
    dst[32] = mrun; dst[33] = lrun;
  }
  __syncthreads();
  if (wid == 0) {
    const float* src = &clds[0][l][0];
    const float mb = src[32], lb = src[33];
    const float M = fmaxf(mrun, mb);
    const float ca = exp2f(mrun - M), cb = exp2f(mb - M);
    lrun = lrun * ca + lb * cb;
    const float inv = 1.f / lrun;
    float* orow = out + (size_t)(b * 2048 + q0 + lc) * 1024 + h * 64;
#pragma unroll
    for (int g = 0; g < 4; ++g) {
      f32x4 v0, v1;
#pragma unroll
      for (int e = 0; e < 4; ++e) {
        v0[e] = (o0[g * 4 + e] * ca + src[g * 4 + e] * cb) * inv;
        v1[e] = (o1[g * 4 + e] * ca + src[16 + g * 4 + e] * cb) * inv;
      }
      *reinterpret_cast<f32x4*>(orow + g * 8 + 4 * hi) = v0;
      *reinterpret_cast<f32x4*>(orow + 32 + g * 8 + 4 * hi) = v1;
    }
  }
}

// ---------------------------------------------------------------- launch
extern "C" void kernel_launch(void* const* d_in, const int* in_sizes, int n_in,
                              void* d_out, int out_size, void* d_ws, size_t ws_size,
                              hipStream_t stream) {
  const float* x  = (const float*)d_in[0];
  const float* wq = (const float*)d_in[1];
  const float* bq = (const float*)d_in[2];
  const float* wk = (const float*)d_in[3];
  const float* bk = (const float*)d_in[4];
  const float* wv = (const float*)d_in[5];
  const float* bv = (const float*)d_in[6];
  float* out = (float*)d_out;

  char* ws = (char*)d_ws;
  bf16* xb  = (bf16*)(ws);                    // 8,388,608 B
  bf16* wqb = (bf16*)(ws + 8388608);          // 2,097,152
  bf16* wkb = (bf16*)(ws + 10485760);         // 2,097,152
  bf16* wvb = (bf16*)(ws + 12582912);         // 2,097,152
  bf16* qb  = (bf16*)(ws + 14680064);         // 8,388,608
  bf16* kb  = (bf16*)(ws + 23068672);         // 8,388,608
  bf16* vb  = (bf16*)(ws + 31457280);         // 8,388,608
  bf16* vt  = (bf16*)(ws + 39845888);         // 8,388,608
  float* ctab = (float*)(ws + 48234496);      // 262,144
  float* stab = (float*)(ws + 48496640);      // 262,144

  prep_kernel<<<7424, 256, 0, stream>>>(x, wq, wk, wv, xb, wqb, wkb, wvb,
                                        ctab, stab);

  qkv_gemm_kernel<<<dim3(32, 8, 3), 256, 0, stream>>>(
      xb, wqb, wkb, wvb, bq, bk, bv, ctab, stab, qb, kb, vb);

  vtrans_kernel<<<dim3(32, 32), 256, 0, stream>>>(vb, vt);

  attn_kernel<<<2048, 256, 0, stream>>>(qb, kb, vt, out);
}

// Round 4
// 218.943 us; speedup vs baseline: 1.4184x; 1.1740x over previous
//
#include <hip/hip_runtime.h>

// Problem constants: B=2, S=2048, D=1024, H=16, HD=64, M = B*S = 4096

typedef __bf16 bf16;
typedef bf16  bf16x8 __attribute__((ext_vector_type(8)));
typedef bf16  bf16x4 __attribute__((ext_vector_type(4)));
typedef float f32x4  __attribute__((ext_vector_type(4)));
typedef float f32x16 __attribute__((ext_vector_type(16)));

typedef const __attribute__((address_space(1))) void* gptr_t;
typedef __attribute__((address_space(3))) void*       sptr_t;

__device__ __forceinline__ void gload_lds16(const void* g, void* l) {
  __builtin_amdgcn_global_load_lds((gptr_t)g, (sptr_t)l, 16, 0, 0);
}

// ------------------------------------------------- fused prep: f2bf x4 + rope
__global__ __launch_bounds__(256) void prep_kernel(
    const float* __restrict__ x, const float* __restrict__ wq,
    const float* __restrict__ wk, const float* __restrict__ wv,
    bf16* __restrict__ xb, bf16* __restrict__ wqb, bf16* __restrict__ wkb,
    bf16* __restrict__ wvb, float* __restrict__ ctab, float* __restrict__ stab) {
  int g = blockIdx.x * 256 + threadIdx.x;
  const float* src;
  bf16* dst;
  int i;
  if (g < 1048576) { src = x; dst = xb; i = g; }
  else if (g < 1310720) { src = wq; dst = wqb; i = g - 1048576; }
  else if (g < 1572864) { src = wk; dst = wkb; i = g - 1310720; }
  else if (g < 1835008) { src = wv; dst = wvb; i = g - 1572864; }
  else {
    int idx = g - 1835008;
    if (idx < 65536) {
      int s = idx >> 5, p = idx & 31;
      double theta = exp2(-(double)p * (13.287712379549449 / 32.0));
      double ang = (double)s * theta;
      ctab[idx] = (float)cos(ang);
      stab[idx] = (float)sin(ang);
    }
    return;
  }
  const float4 v = reinterpret_cast<const float4*>(src)[i];
  bf16x4 o;
  o[0] = (bf16)v.x; o[1] = (bf16)v.y; o[2] = (bf16)v.z; o[3] = (bf16)v.w;
  reinterpret_cast<bf16x4*>(dst)[i] = o;
}

// ---------------------------------------------------------------- QKV GEMM
__global__ __launch_bounds__(256) void qkv_gemm_kernel(
    const bf16* __restrict__ xb, const bf16* __restrict__ wqb,
    const bf16* __restrict__ wkb, const bf16* __restrict__ wvb,
    const float* __restrict__ bq, const float* __restrict__ bk2,
    const float* __restrict__ bv, const float* __restrict__ ctab,
    const float* __restrict__ stab, bf16* __restrict__ qb,
    bf16* __restrict__ kb, bf16* __restrict__ vb) {
  const int z = blockIdx.z;
  const bf16* W = (z == 0) ? wqb : (z == 1) ? wkb : wvb;
  const float* bias = (z == 0) ? bq : (z == 1) ? bk2 : bv;
  bf16* dst = (z == 0) ? qb : (z == 1) ? kb : vb;

  __shared__ bf16 As[128 * 32];
  __shared__ bf16 Bs[128 * 32];

  const int tid = threadIdx.x;
  const int wid = tid >> 6;
  const int l = tid & 63;
  const int lg = l >> 4, lc = l & 15;
  const int wr = wid >> 1, wc = wid & 1;
  const int m0 = blockIdx.x * 128, n0 = blockIdx.y * 128;

  f32x4 acc[4][4] = {};

  const int arow = tid >> 2;
  const int acol = (tid & 3) * 8;
  const bf16* asrc = xb + (size_t)(m0 + arow) * 1024 + acol;
  const bf16* bsrc = W + (size_t)(n0 + arow) * 1024 + acol;
  char* alds = (char*)As + wid * 1024;
  char* blds = (char*)Bs + wid * 1024;

  for (int k0 = 0; k0 < 1024; k0 += 32) {
    gload_lds16(asrc + k0, alds);
    gload_lds16(asrc + 64 * 1024 + k0, alds + 4096);
    gload_lds16(bsrc + k0, blds);
    gload_lds16(bsrc + 64 * 1024 + k0, blds + 4096);
    __syncthreads();
    bf16x8 af[4], bfr[4];
#pragma unroll
    for (int i = 0; i < 4; ++i)
      af[i] = *reinterpret_cast<const bf16x8*>(
          (const char*)As + ((wr * 64 + i * 16 + lc) * 64 + lg * 16));
#pragma unroll
    for (int j = 0; j < 4; ++j)
      bfr[j] = *reinterpret_cast<const bf16x8*>(
          (const char*)Bs + ((wc * 64 + j * 16 + lc) * 64 + lg * 16));
#pragma unroll
    for (int i = 0; i < 4; ++i)
#pragma unroll
      for (int j = 0; j < 4; ++j)
        acc[i][j] = __builtin_amdgcn_mfma_f32_16x16x32_bf16(af[i], bfr[j],
                                                            acc[i][j], 0, 0, 0);
    __syncthreads();
  }

#pragma unroll
  for (int i = 0; i < 4; ++i)
#pragma unroll
    for (int j = 0; j < 4; ++j) {
      const int nb = n0 + wc * 64 + j * 16 + lc;
      const float bval = bias[nb];
#pragma unroll
      for (int r = 0; r < 4; ++r) {
        const int m = m0 + wr * 64 + i * 16 + lg * 4 + r;
        const float val = acc[i][j][r] + bval;
        if (z == 2) {
          dst[(size_t)m * 1024 + nb] = (bf16)val;
        } else {
          const int s = m & 2047;
          const int pi = (nb & 63) >> 1;
          const float c = ctab[s * 32 + pi];
          const float sn = stab[s * 32 + pi];
          const float part = __shfl_xor(val, 1, 64);
          float res = (nb & 1) ? fmaf(part, sn, val * c)
                               : fmaf(-part, sn, val * c);
          if (z == 0) res *= 0.18033688011112042f;  // (1/8) * log2(e)
          dst[(size_t)m * 1024 + nb] = (bf16)res;
        }
      }
    }
}

// ---------------------------------------------------------------- V transpose
// vb [4096][1024] -> vt [bh=32][hd=64][s=2048]
__global__ __launch_bounds__(256) void vtrans_kernel(const bf16* __restrict__ vb,
                                                     bf16* __restrict__ vt) {
  __shared__ bf16 tile[64][65];
  const int bh = blockIdx.y, b = bh >> 4, h = bh & 15;
  const int s0 = blockIdx.x * 64;
  const int t = threadIdx.x;
#pragma unroll
  for (int idx = t; idx < 4096; idx += 256) {
    int r = idx >> 6, c = idx & 63;
    tile[r][c] = vb[(size_t)(b * 2048 + s0 + r) * 1024 + h * 64 + c];
  }
  __syncthreads();
#pragma unroll
  for (int idx = t; idx < 4096; idx += 256) {
    int d = idx >> 6, r = idx & 63;
    vt[(size_t)(bh * 64 + d) * 2048 + s0 + r] = tile[r][d];
  }
}

// ---------------------------------------------------------------- pack helper
__device__ __forceinline__ unsigned pkbf(float a, float b) {
  union { bf16 h[2]; unsigned u; } t;
  t.h[0] = (bf16)a; t.h[1] = (bf16)b;
  return t.u;
}

// ---------------------------------------------------------------- Attention v4
// 4 waves x 32 q-rows (128 q/block), all waves sweep the full KV range.
// K/V staged in LDS (KVBLK=64, double-buffered, global_load_lds w16), XOR
// swizzle both-sides (pre-swizzled source chunk + swizzled ds_read).
// Swapped QK^T (32x32x16), in-register online softmax (exp2 domain).
__global__ __launch_bounds__(256) void attn_kernel(const bf16* __restrict__ qb,
                                                   const bf16* __restrict__ kb,
                                                   const bf16* __restrict__ vt,
                                                   float* __restrict__ out) {
  __shared__ bf16 Kt[2][64][64];
  __shared__ bf16 Vt[2][64][64];

  const int tid = threadIdx.x;
  const int wid = tid >> 6;
  const int l = tid & 63;
  const int lc = l & 31;      // q index within tile (MFMA C col)
  const int hi = l >> 5;      // half-wave
  // XCD swizzle over 512 blocks -> 4 heads per XCD (K/V L2-resident)
  const int bid = blockIdx.x;
  const int swz = (bid & 7) * 64 + (bid >> 3);
  const int bh = swz >> 4;          // 0..31
  const int qt = swz & 15;          // 0..15
  const int b = bh >> 4, h = bh & 15;
  const int q0 = qt * 128 + wid * 32;

  const bf16* Q = qb + (size_t)(b * 2048 + q0) * 1024 + h * 64;
  const bf16* K = kb + (size_t)(b * 2048) * 1024 + h * 64;
  const bf16* V = vt + (size_t)bh * 64 * 2048;

  // Q fragment (B-operand of QK^T): qf[md][t] = Q[q0+lc][md*16 + hi*8 + t]
  bf16x8 qf[4];
#pragma unroll
  for (int md = 0; md < 4; ++md)
    qf[md] = *reinterpret_cast<const bf16x8*>(Q + (size_t)lc * 1024 + md * 16 + hi * 8);

  // Staging geometry: each wave stages rows [wid*16, wid*16+16) of both tiles.
  // LDS[row][chunk] = global[row][chunk ^ (row&7)]  (16B chunks, 8 per row)
  const int srow = l >> 3;                  // local row within 8-row group
  const int schk = (l & 7) ^ (srow & 7);    // pre-swizzled source chunk
  const bf16* ksrc0 = K + (size_t)(wid * 16 + srow) * 1024 + schk * 8;
  const bf16* ksrc1 = ksrc0 + (size_t)8 * 1024;
  const bf16* vsrc0 = V + (size_t)(wid * 16 + srow) * 2048 + schk * 8;
  const bf16* vsrc1 = vsrc0 + (size_t)8 * 2048;

  f32x16 o0 = {};  // O^T rows d = 0..31  (d = (r&3)+8*(r>>2)+4*hi)
  f32x16 o1 = {};  // O^T rows d = 32..63
  float mrun = -1e30f, lrun = 0.f;
  const int sb = (hi ^ 1) * 2;  // exchange pre-select base
  const int swzk = lc & 7;      // read-side XOR key (row&7 == lc&7)

  // prologue: stage tile 0 into buffer 0
  gload_lds16(ksrc0, &Kt[0][wid * 16][0]);
  gload_lds16(ksrc1, &Kt[0][wid * 16 + 8][0]);
  gload_lds16(vsrc0, &Vt[0][wid * 16][0]);
  gload_lds16(vsrc1, &Vt[0][wid * 16 + 8][0]);
  __syncthreads();

  int bb = 0;
  for (int kt0 = 0; kt0 < 32; ++kt0) {
    if (kt0 < 31) {
      const size_t ko = (size_t)(kt0 + 1) * 64 * 1024;
      const size_t vo = (size_t)(kt0 + 1) * 64;
      gload_lds16(ksrc0 + ko, &Kt[bb ^ 1][wid * 16][0]);
      gload_lds16(ksrc1 + ko, &Kt[bb ^ 1][wid * 16 + 8][0]);
      gload_lds16(vsrc0 + vo, &Vt[bb ^ 1][wid * 16][0]);
      gload_lds16(vsrc1 + vo, &Vt[bb ^ 1][wid * 16 + 8][0]);
    }
#pragma unroll
    for (int sub = 0; sub < 2; ++sub) {
      // ---- S^T tile [32 k][32 q]: A = K rows (from LDS), B = Q
      f32x16 s = {};
#pragma unroll
      for (int md = 0; md < 4; ++md) {
        bf16x8 kf = *reinterpret_cast<const bf16x8*>(
            &Kt[bb][sub * 32 + lc][(((md << 1) | hi) ^ swzk) << 3]);
        s = __builtin_amdgcn_mfma_f32_32x32x16_bf16(kf, qf[md], s, 0, 0, 0);
      }

      // ---- online softmax (exp2 domain)
      float tm = s[0];
#pragma unroll
      for (int r = 1; r < 16; ++r) tm = fmaxf(tm, s[r]);
      tm = fmaxf(tm, __shfl_xor(tm, 32, 64));
      if (!__all(tm <= mrun + 8.0f)) {   // T13 defer-max
        const float mn = fmaxf(mrun, tm);
        const float corr = exp2f(mrun - mn);
        mrun = mn;
        lrun *= corr;
#pragma unroll
        for (int r = 0; r < 16; ++r) { o0[r] *= corr; o1[r] *= corr; }
      }
      float ts = 0.f;
#pragma unroll
      for (int r = 0; r < 16; ++r) {
        s[r] = exp2f(s[r] - mrun);
        ts += s[r];
      }
      ts += __shfl_xor(ts, 32, 64);
      lrun += ts;

      // ---- pack P^T to bf16 pairs and exchange halves
      unsigned pw[8];
#pragma unroll
      for (int w = 0; w < 8; ++w) pw[w] = pkbf(s[2 * w], s[2 * w + 1]);

      unsigned rx0 = __shfl_xor(pw[sb + 0], 32, 64);
      unsigned rx1 = __shfl_xor(pw[sb + 1], 32, 64);
      unsigned rx2 = __shfl_xor(pw[4 + sb + 0], 32, 64);
      unsigned rx3 = __shfl_xor(pw[4 + sb + 1], 32, 64);

      union { unsigned u[4]; bf16x8 v; } bf0, bf1;
      if (hi == 0) {
        bf0.u[0] = pw[0]; bf0.u[1] = pw[1]; bf0.u[2] = rx0; bf0.u[3] = rx1;
        bf1.u[0] = pw[4]; bf1.u[1] = pw[5]; bf1.u[2] = rx2; bf1.u[3] = rx3;
      } else {
        bf0.u[0] = rx0; bf0.u[1] = rx1; bf0.u[2] = pw[2]; bf0.u[3] = pw[3];
        bf1.u[0] = rx2; bf1.u[1] = rx3; bf1.u[2] = pw[6]; bf1.u[3] = pw[7];
      }

      // ---- PV: A = V^T rows (from LDS), k = 16 per MFMA
      const int vc = sub * 4 + hi;
      bf16x8 vf00 = *reinterpret_cast<const bf16x8*>(
          &Vt[bb][lc][((vc ^ swzk)) << 3]);
      bf16x8 vf01 = *reinterpret_cast<const bf16x8*>(
          &Vt[bb][lc][(((vc + 2) ^ swzk)) << 3]);
      bf16x8 vf10 = *reinterpret_cast<const bf16x8*>(
          &Vt[bb][lc + 32][((vc ^ swzk)) << 3]);
      bf16x8 vf11 = *reinterpret_cast<const bf16x8*>(
          &Vt[bb][lc + 32][(((vc + 2) ^ swzk)) << 3]);
      o0 = __builtin_amdgcn_mfma_f32_32x32x16_bf16(vf00, bf0.v, o0, 0, 0, 0);
      o0 = __builtin_amdgcn_mfma_f32_32x32x16_bf16(vf01, bf1.v, o0, 0, 0, 0);
      o1 = __builtin_amdgcn_mfma_f32_32x32x16_bf16(vf10, bf0.v, o1, 0, 0, 0);
      o1 = __builtin_amdgcn_mfma_f32_32x32x16_bf16(vf11, bf1.v, o1, 0, 0, 0);
    }
    __syncthreads();
    bb ^= 1;
  }

  // ---- epilogue: out[b][q][h*64+d] = O^T[d][q] / lrun, f32x4 stores
  const float inv = 1.f / lrun;
  float* orow = out + (size_t)(b * 2048 + q0 + lc) * 1024 + h * 64;
#pragma unroll
  for (int g = 0; g < 4; ++g) {
    f32x4 v0, v1;
#pragma unroll
    for (int e = 0; e < 4; ++e) { v0[e] = o0[g * 4 + e] * inv; v1[e] = o1[g * 4 + e] * inv; }
    *reinterpret_cast<f32x4*>(orow + g * 8 + 4 * hi) = v0;
    *reinterpret_cast<f32x4*>(orow + 32 + g * 8 + 4 * hi) = v1;
  }
}

// ---------------------------------------------------------------- launch
extern "C" void kernel_launch(void* const* d_in, const int* in_sizes, int n_in,
                              void* d_out, int out_size, void* d_ws, size_t ws_size,
                              hipStream_t stream) {
  const float* x  = (const float*)d_in[0];
  const float* wq = (const float*)d_in[1];
  const float* bq = (const float*)d_in[2];
  const float* wk = (const float*)d_in[3];
  const float* bk = (const float*)d_in[4];
  const float* wv = (const float*)d_in[5];
  const float* bv = (const float*)d_in[6];
  float* out = (float*)d_out;

  char* ws = (char*)d_ws;
  bf16* xb  = (bf16*)(ws);                    // 8,388,608 B
  bf16* wqb = (bf16*)(ws + 8388608);          // 2,097,152
  bf16* wkb = (bf16*)(ws + 10485760);         // 2,097,152
  bf16* wvb = (bf16*)(ws + 12582912);         // 2,097,152
  bf16* qb  = (bf16*)(ws + 14680064);         // 8,388,608
  bf16* kb  = (bf16*)(ws + 23068672);         // 8,388,608
  bf16* vb  = (bf16*)(ws + 31457280);         // 8,388,608
  bf16* vt  = (bf16*)(ws + 39845888);         // 8,388,608
  float* ctab = (float*)(ws + 48234496);      // 262,144
  float* stab = (float*)(ws + 48496640);      // 262,144

  prep_kernel<<<7424, 256, 0, stream>>>(x, wq, wk, wv, xb, wqb, wkb, wvb,
                                        ctab, stab);

  qkv_gemm_kernel<<<dim3(32, 8, 3), 256, 0, stream>>>(
      xb, wqb, wkb, wvb, bq, bk, bv, ctab, stab, qb, kb, vb);

  vtrans_kernel<<<dim3(32, 32), 256, 0, stream>>>(vb, vt);

  attn_kernel<<<512, 256, 0, stream>>>(qb, kb, vt, out);
}